// Round 15
// baseline (43.047 us; speedup 1.0000x reference)
//
#include <hip/hip_runtime.h>
#include <math.h>

// LearnedDRoPEEnergy: B=16, K=256, H=W=64, T=1.0
// R15 = R13 VERBATIM (best: 24.7us) + energy launched 3x (diagnostic).
// Launches 1,2 -> scratch out in d_ws (unused); launch 3 -> real out.
// dur_R15 - dur_R13 = 2 x energy_warm. Closes the energy-vs-fixed split
// the same way R12's pack x3 closed pack (= 9.6us, HBM ceiling).
#define NPOS 65536

typedef float floatx4 __attribute__((ext_vector_type(4)));

// 8 representative offsets (other 8 are negatives; d and gate symmetric,
// torus sum translation-invariant -> x2). Verified R2/R4-R14 (absmax=0).
__device__ __constant__ int c_dy8[8] = {-1, 0, -1, -1, -2,  0, -2, -2};
__device__ __constant__ int c_dx8[8] = { 0,-1, -1,  1,  0, -2, -2,  2};

// Kernel A: pack (R8 verbatim; 9.6us measured, HBM ceiling, closed).
__global__ __launch_bounds__(256) void pack_kernel(const float* __restrict__ z,
                                                   unsigned* __restrict__ packu32,
                                                   float* __restrict__ out) {
    int tid = threadIdx.x;
    unsigned beta = blockIdx.x;                 // 0..255 = b*16 + q
    const float* base = z + ((size_t)beta << 16);   // beta * 16*4096 floats
    unsigned acc[16];
#pragma unroll
    for (int t = 0; t < 16; ++t) acc[t] = 0u;
#pragma unroll
    for (int j = 0; j < 16; ++j) {              // plane within group (bit j)
#pragma unroll
        for (int i = 0; i < 4; ++i) {           // position chunk
            floatx4 v = __builtin_nontemporal_load(
                (const floatx4*)(base + (j << 12) + (i << 10) + (tid << 2)));
            unsigned bit = 1u << j;
            if (v.x != 0.0f) acc[i * 4 + 0] |= bit;
            if (v.y != 0.0f) acc[i * 4 + 1] |= bit;
            if (v.z != 0.0f) acc[i * 4 + 2] |= bit;
            if (v.w != 0.0f) acc[i * 4 + 3] |= bit;
        }
    }
    unsigned* dst = packu32 + ((size_t)beta << 11);   // beta*4096 u16
#pragma unroll
    for (int i = 0; i < 4; ++i) {
        unsigned lo = acc[i * 4 + 0] | (acc[i * 4 + 1] << 16);
        unsigned hi = acc[i * 4 + 2] | (acc[i * 4 + 3] << 16);
        *(uint2*)(dst + (i << 9) + (tid << 1)) = make_uint2(lo, hi);
    }
    if (beta == 0 && tid < 16) out[tid] = 0.0f;
}

// Kernel B: energy (R13 verbatim). 256 blocks x 1024 threads; thread =
// (pos, 2-offset group); in-block LUT; q-major u16 loads; x2 symmetry.
__global__ __launch_bounds__(1024) void energy_kernel(const unsigned short* __restrict__ p16,
                                                      const float* __restrict__ w_logit,
                                                      const float* __restrict__ tau_p,
                                                      float* __restrict__ out) {
    __shared__ float wtab[32 * 256];   // 32 KB byte-LUT: wtab[p][v], p = k/8
    __shared__ float ws[256];          // softplus(w_logit[k])
    __shared__ float red[16];

    int tid = threadIdx.x;             // 0..1023
    if (tid < 256) ws[tid] = log1pf(expf(w_logit[tid]));   // softplus, fp32
    __syncthreads();
    {   // LUT: 8192 entries / 1024 threads = 8 each
        int p = tid >> 5;
        int vbase = (tid & 31) * 8;
        float wv[8];
#pragma unroll
        for (int j = 0; j < 8; ++j) wv[j] = ws[p * 8 + j];
#pragma unroll
        for (int v = vbase; v < vbase + 8; ++v) {
            float s = 0.0f;
#pragma unroll
            for (int j = 0; j < 8; ++j) s += ((v >> j) & 1) ? wv[j] : 0.0f;
            wtab[p * 256 + v] = s;
        }
    }
    __syncthreads();

    float tau = tau_p[0];
    int og = tid >> 8;                   // 0..3, uniform per wave
    int pi = tid & 255;
    int pos = blockIdx.x * 256 + pi;     // one (pos, og) pair per thread
    int b  = pos >> 12;                  // uniform per block
    int hw = pos & 4095;
    int h  = hw >> 6;
    int w  = hw & 63;

    const unsigned short* pb = p16 + ((size_t)b << 16);  // b's 16 groups * 4096

    unsigned cw[16];                     // center words
#pragma unroll
    for (int q = 0; q < 16; ++q) cw[q] = pb[(q << 12) + hw];

    float e = 0.0f;
#pragma unroll
    for (int oo = 0; oo < 2; ++oo) {
        int o = og * 2 + oo;
        int h2 = (h + c_dy8[o]) & 63;
        int w2 = (w + c_dx8[o]) & 63;
        int hw2 = (h2 << 6) | w2;
        float d0 = 0.0f, d1 = 0.0f;
#pragma unroll
        for (int q = 0; q < 16; ++q) {
            unsigned x = cw[q] ^ (unsigned)pb[(q << 12) + hw2];  // u16 XOR
            d0 += wtab[(2 * q + 0) * 256 + (x & 255)];
            d1 += wtab[(2 * q + 1) * 256 + (x >> 8)];
        }
        float d = d0 + d1;
        // gate*d = d / (1 + exp(d - tau)); exp overflow -> inf -> 0, correct
        e += d / (1.0f + expf(d - tau));
    }

    // block reduction over 16 waves (b uniform per block); x2 symmetry
#pragma unroll
    for (int s = 32; s > 0; s >>= 1) e += __shfl_down(e, s, 64);
    int lane = tid & 63, wv2 = tid >> 6;
    if (lane == 0) red[wv2] = e;
    __syncthreads();
    if (tid == 0) {
        float s = 0.0f;
#pragma unroll
        for (int i = 0; i < 16; ++i) s += red[i];
        atomicAdd(out + b, 2.0f * s);
    }
}

extern "C" void kernel_launch(void* const* d_in, const int* in_sizes, int n_in,
                              void* d_out, int out_size, void* d_ws, size_t ws_size,
                              hipStream_t stream) {
    const float* z       = (const float*)d_in[0];   // (B,K,H,W) fp32 0/1
    const float* w_logit = (const float*)d_in[1];   // (K,)
    const float* tau     = (const float*)d_in[2];   // scalar
    float* out = (float*)d_out;                     // (B,)
    unsigned* packu32 = (unsigned*)d_ws;            // 2 MB, q-major u16 layout
    float* scratch_out = (float*)((char*)d_ws + (8 * NPOS * 4));  // +16 floats, unused

    hipLaunchKernelGGL(pack_kernel, dim3(256), dim3(256), 0, stream,
                       z, packu32, out);
    // DIAGNOSTIC: energy 3x; first two accumulate into scratch (never read),
    // third writes the real out (zeroed by pack this replay). Deterministic
    // final output; dur - R13 = 2 x energy_warm.
    hipLaunchKernelGGL(energy_kernel, dim3(256), dim3(1024), 0, stream,
                       (const unsigned short*)packu32, w_logit, tau, scratch_out);
    hipLaunchKernelGGL(energy_kernel, dim3(256), dim3(1024), 0, stream,
                       (const unsigned short*)packu32, w_logit, tau, scratch_out);
    hipLaunchKernelGGL(energy_kernel, dim3(256), dim3(1024), 0, stream,
                       (const unsigned short*)packu32, w_logit, tau, out);
}

// Round 16
// 26.066 us; speedup vs baseline: 1.6514x; 1.6514x over previous
//
#include <hip/hip_runtime.h>
#include <math.h>

// LearnedDRoPEEnergy: B=16, K=256, H=W=64, T=1.0
// R16 = R13 verbatim with ONE change: pack loads are PLAIN (no nontemporal).
// Theory: z (67MB) fits in 256MB L3 across replays; nt marks lines
// evict-first and blocks retention (R10 counters: FETCH=34MB, only half
// absorbed). Plain loads -> full L3 retention -> pack below HBM time.
// Ledger (measured): pack ~9.6us (R12 x3), energy ~9.2us (R15 x3), fixed ~6.
#define NPOS 65536

typedef float floatx4 __attribute__((ext_vector_type(4)));

// 8 representative offsets (other 8 are negatives; d and gate symmetric,
// torus sum translation-invariant -> x2). Verified R2/R4-R15 (absmax=0).
__device__ __constant__ int c_dy8[8] = {-1, 0, -1, -1, -2,  0, -2, -2};
__device__ __constant__ int c_dx8[8] = { 0,-1, -1,  1,  0, -2, -2,  2};

// Kernel A: pack. Block beta owns 16 consecutive k-planes = one unbroken
// 256KB region; ascending sweep; register transpose; coalesced uint2 stores.
__global__ __launch_bounds__(256) void pack_kernel(const float* __restrict__ z,
                                                   unsigned* __restrict__ packu32,
                                                   float* __restrict__ out) {
    int tid = threadIdx.x;
    unsigned beta = blockIdx.x;                 // 0..255 = b*16 + q
    const float* base = z + ((size_t)beta << 16);   // beta * 16*4096 floats
    unsigned acc[16];
#pragma unroll
    for (int t = 0; t < 16; ++t) acc[t] = 0u;
#pragma unroll
    for (int j = 0; j < 16; ++j) {              // plane within group (bit j)
#pragma unroll
        for (int i = 0; i < 4; ++i) {           // position chunk
            floatx4 v = *(const floatx4*)(base + (j << 12) + (i << 10) + (tid << 2));
            unsigned bit = 1u << j;
            if (v.x != 0.0f) acc[i * 4 + 0] |= bit;
            if (v.y != 0.0f) acc[i * 4 + 1] |= bit;
            if (v.z != 0.0f) acc[i * 4 + 2] |= bit;
            if (v.w != 0.0f) acc[i * 4 + 3] |= bit;
        }
    }
    unsigned* dst = packu32 + ((size_t)beta << 11);   // beta*4096 u16
#pragma unroll
    for (int i = 0; i < 4; ++i) {
        unsigned lo = acc[i * 4 + 0] | (acc[i * 4 + 1] << 16);
        unsigned hi = acc[i * 4 + 2] | (acc[i * 4 + 3] << 16);
        *(uint2*)(dst + (i << 9) + (tid << 1)) = make_uint2(lo, hi);
    }
    if (beta == 0 && tid < 16) out[tid] = 0.0f;
}

// Kernel B: energy (R13 verbatim). 256 blocks x 1024 threads; thread =
// (pos, 2-offset group); in-block LUT; q-major u16 loads; x2 symmetry.
__global__ __launch_bounds__(1024) void energy_kernel(const unsigned short* __restrict__ p16,
                                                      const float* __restrict__ w_logit,
                                                      const float* __restrict__ tau_p,
                                                      float* __restrict__ out) {
    __shared__ float wtab[32 * 256];   // 32 KB byte-LUT: wtab[p][v], p = k/8
    __shared__ float ws[256];          // softplus(w_logit[k])
    __shared__ float red[16];

    int tid = threadIdx.x;             // 0..1023
    if (tid < 256) ws[tid] = log1pf(expf(w_logit[tid]));   // softplus, fp32
    __syncthreads();
    {   // LUT: 8192 entries / 1024 threads = 8 each
        int p = tid >> 5;
        int vbase = (tid & 31) * 8;
        float wv[8];
#pragma unroll
        for (int j = 0; j < 8; ++j) wv[j] = ws[p * 8 + j];
#pragma unroll
        for (int v = vbase; v < vbase + 8; ++v) {
            float s = 0.0f;
#pragma unroll
            for (int j = 0; j < 8; ++j) s += ((v >> j) & 1) ? wv[j] : 0.0f;
            wtab[p * 256 + v] = s;
        }
    }
    __syncthreads();

    float tau = tau_p[0];
    int og = tid >> 8;                   // 0..3, uniform per wave
    int pi = tid & 255;
    int pos = blockIdx.x * 256 + pi;     // one (pos, og) pair per thread
    int b  = pos >> 12;                  // uniform per block
    int hw = pos & 4095;
    int h  = hw >> 6;
    int w  = hw & 63;

    const unsigned short* pb = p16 + ((size_t)b << 16);  // b's 16 groups * 4096

    unsigned cw[16];                     // center words
#pragma unroll
    for (int q = 0; q < 16; ++q) cw[q] = pb[(q << 12) + hw];

    float e = 0.0f;
#pragma unroll
    for (int oo = 0; oo < 2; ++oo) {
        int o = og * 2 + oo;
        int h2 = (h + c_dy8[o]) & 63;
        int w2 = (w + c_dx8[o]) & 63;
        int hw2 = (h2 << 6) | w2;
        float d0 = 0.0f, d1 = 0.0f;
#pragma unroll
        for (int q = 0; q < 16; ++q) {
            unsigned x = cw[q] ^ (unsigned)pb[(q << 12) + hw2];  // u16 XOR
            d0 += wtab[(2 * q + 0) * 256 + (x & 255)];
            d1 += wtab[(2 * q + 1) * 256 + (x >> 8)];
        }
        float d = d0 + d1;
        // gate*d = d / (1 + exp(d - tau)); exp overflow -> inf -> 0, correct
        e += d / (1.0f + expf(d - tau));
    }

    // block reduction over 16 waves (b uniform per block); x2 symmetry
#pragma unroll
    for (int s = 32; s > 0; s >>= 1) e += __shfl_down(e, s, 64);
    int lane = tid & 63, wv2 = tid >> 6;
    if (lane == 0) red[wv2] = e;
    __syncthreads();
    if (tid == 0) {
        float s = 0.0f;
#pragma unroll
        for (int i = 0; i < 16; ++i) s += red[i];
        atomicAdd(out + b, 2.0f * s);
    }
}

extern "C" void kernel_launch(void* const* d_in, const int* in_sizes, int n_in,
                              void* d_out, int out_size, void* d_ws, size_t ws_size,
                              hipStream_t stream) {
    const float* z       = (const float*)d_in[0];   // (B,K,H,W) fp32 0/1
    const float* w_logit = (const float*)d_in[1];   // (K,)
    const float* tau     = (const float*)d_in[2];   // scalar
    float* out = (float*)d_out;                     // (B,)
    unsigned* packu32 = (unsigned*)d_ws;            // 2 MB, q-major u16 layout

    hipLaunchKernelGGL(pack_kernel, dim3(256), dim3(256), 0, stream,
                       z, packu32, out);
    hipLaunchKernelGGL(energy_kernel, dim3(256), dim3(1024), 0, stream,
                       (const unsigned short*)packu32, w_logit, tau, out);
}

// Round 17
// 24.680 us; speedup vs baseline: 1.7442x; 1.0562x over previous
//
#include <hip/hip_runtime.h>
#include <math.h>

// LearnedDRoPEEnergy: B=16, K=256, H=W=64, T=1.0
// R17 = R13 VERBATIM (best measured: 24.7us). R16 falsified the no-nt
// variant (+1.4us); nt loads restored.
// Ledger (measured): pack ~9.6us (R12 x3, ~HBM ceiling, half L3-served),
// energy ~9.2us (R15 x3, ~1.8x above random-gather LDS floor),
// fixed/dispatch ~5.9us.
#define NPOS 65536

typedef float floatx4 __attribute__((ext_vector_type(4)));

// 8 representative offsets (other 8 are negatives; d and gate symmetric,
// torus sum translation-invariant -> x2). Verified R2/R4-R16 (absmax=0).
__device__ __constant__ int c_dy8[8] = {-1, 0, -1, -1, -2,  0, -2, -2};
__device__ __constant__ int c_dx8[8] = { 0,-1, -1,  1,  0, -2, -2,  2};

// Kernel A: pack (R8 verbatim). Block beta owns 16 consecutive k-planes =
// one unbroken 256KB region of z; ascending sweep; nontemporal loads;
// register transpose; coalesced uint2 stores. q-major u16 output layout.
__global__ __launch_bounds__(256) void pack_kernel(const float* __restrict__ z,
                                                   unsigned* __restrict__ packu32,
                                                   float* __restrict__ out) {
    int tid = threadIdx.x;
    unsigned beta = blockIdx.x;                 // 0..255 = b*16 + q
    const float* base = z + ((size_t)beta << 16);   // beta * 16*4096 floats
    unsigned acc[16];
#pragma unroll
    for (int t = 0; t < 16; ++t) acc[t] = 0u;
#pragma unroll
    for (int j = 0; j < 16; ++j) {              // plane within group (bit j)
#pragma unroll
        for (int i = 0; i < 4; ++i) {           // position chunk
            floatx4 v = __builtin_nontemporal_load(
                (const floatx4*)(base + (j << 12) + (i << 10) + (tid << 2)));
            unsigned bit = 1u << j;
            if (v.x != 0.0f) acc[i * 4 + 0] |= bit;
            if (v.y != 0.0f) acc[i * 4 + 1] |= bit;
            if (v.z != 0.0f) acc[i * 4 + 2] |= bit;
            if (v.w != 0.0f) acc[i * 4 + 3] |= bit;
        }
    }
    unsigned* dst = packu32 + ((size_t)beta << 11);   // beta*4096 u16
#pragma unroll
    for (int i = 0; i < 4; ++i) {
        unsigned lo = acc[i * 4 + 0] | (acc[i * 4 + 1] << 16);
        unsigned hi = acc[i * 4 + 2] | (acc[i * 4 + 3] << 16);
        *(uint2*)(dst + (i << 9) + (tid << 1)) = make_uint2(lo, hi);
    }
    if (beta == 0 && tid < 16) out[tid] = 0.0f;
}

// Kernel B: energy (R13 verbatim). 256 blocks x 1024 threads; thread =
// (pos, 2-offset group); in-block byte-LUT (softplus shared via LDS);
// q-major u16 loads; x2 symmetry; one atomic per block.
__global__ __launch_bounds__(1024) void energy_kernel(const unsigned short* __restrict__ p16,
                                                      const float* __restrict__ w_logit,
                                                      const float* __restrict__ tau_p,
                                                      float* __restrict__ out) {
    __shared__ float wtab[32 * 256];   // 32 KB byte-LUT: wtab[p][v], p = k/8
    __shared__ float ws[256];          // softplus(w_logit[k])
    __shared__ float red[16];

    int tid = threadIdx.x;             // 0..1023
    if (tid < 256) ws[tid] = log1pf(expf(w_logit[tid]));   // softplus, fp32
    __syncthreads();
    {   // LUT: 8192 entries / 1024 threads = 8 each
        int p = tid >> 5;
        int vbase = (tid & 31) * 8;
        float wv[8];
#pragma unroll
        for (int j = 0; j < 8; ++j) wv[j] = ws[p * 8 + j];
#pragma unroll
        for (int v = vbase; v < vbase + 8; ++v) {
            float s = 0.0f;
#pragma unroll
            for (int j = 0; j < 8; ++j) s += ((v >> j) & 1) ? wv[j] : 0.0f;
            wtab[p * 256 + v] = s;
        }
    }
    __syncthreads();

    float tau = tau_p[0];
    int og = tid >> 8;                   // 0..3, uniform per wave
    int pi = tid & 255;
    int pos = blockIdx.x * 256 + pi;     // one (pos, og) pair per thread
    int b  = pos >> 12;                  // uniform per block
    int hw = pos & 4095;
    int h  = hw >> 6;
    int w  = hw & 63;

    const unsigned short* pb = p16 + ((size_t)b << 16);  // b's 16 groups * 4096

    unsigned cw[16];                     // center words
#pragma unroll
    for (int q = 0; q < 16; ++q) cw[q] = pb[(q << 12) + hw];

    float e = 0.0f;
#pragma unroll
    for (int oo = 0; oo < 2; ++oo) {
        int o = og * 2 + oo;
        int h2 = (h + c_dy8[o]) & 63;
        int w2 = (w + c_dx8[o]) & 63;
        int hw2 = (h2 << 6) | w2;
        float d0 = 0.0f, d1 = 0.0f;
#pragma unroll
        for (int q = 0; q < 16; ++q) {
            unsigned x = cw[q] ^ (unsigned)pb[(q << 12) + hw2];  // u16 XOR
            d0 += wtab[(2 * q + 0) * 256 + (x & 255)];
            d1 += wtab[(2 * q + 1) * 256 + (x >> 8)];
        }
        float d = d0 + d1;
        // gate*d = d / (1 + exp(d - tau)); exp overflow -> inf -> 0, correct
        e += d / (1.0f + expf(d - tau));
    }

    // block reduction over 16 waves (b uniform per block); x2 symmetry
#pragma unroll
    for (int s = 32; s > 0; s >>= 1) e += __shfl_down(e, s, 64);
    int lane = tid & 63, wv2 = tid >> 6;
    if (lane == 0) red[wv2] = e;
    __syncthreads();
    if (tid == 0) {
        float s = 0.0f;
#pragma unroll
        for (int i = 0; i < 16; ++i) s += red[i];
        atomicAdd(out + b, 2.0f * s);
    }
}

extern "C" void kernel_launch(void* const* d_in, const int* in_sizes, int n_in,
                              void* d_out, int out_size, void* d_ws, size_t ws_size,
                              hipStream_t stream) {
    const float* z       = (const float*)d_in[0];   // (B,K,H,W) fp32 0/1
    const float* w_logit = (const float*)d_in[1];   // (K,)
    const float* tau     = (const float*)d_in[2];   // scalar
    float* out = (float*)d_out;                     // (B,)
    unsigned* packu32 = (unsigned*)d_ws;            // 2 MB, q-major u16 layout

    hipLaunchKernelGGL(pack_kernel, dim3(256), dim3(256), 0, stream,
                       z, packu32, out);
    hipLaunchKernelGGL(energy_kernel, dim3(256), dim3(1024), 0, stream,
                       (const unsigned short*)packu32, w_logit, tau, out);
}